// Round 8
// baseline (202.197 us; speedup 1.0000x reference)
//
#include <hip/hip_runtime.h>
#include <hip/hip_bf16.h>

#define B_ 2
#define SQ_ 2048
#define SKV_ 2048
#define D_ 1024
#define H_ 16
#define HD_ 64

typedef unsigned short u16;
typedef float f32x4 __attribute__((ext_vector_type(4)));
typedef float f32x16 __attribute__((ext_vector_type(16)));
typedef short s16x8 __attribute__((ext_vector_type(8)));

__device__ __forceinline__ u16 f2bf(float f) {
  union { float f; unsigned u; } v; v.f = f;
  return (u16)((v.u + 0x7FFFu + ((v.u >> 16) & 1u)) >> 16);
}
__device__ __forceinline__ float bf2f(u16 h) {
  union { unsigned u; float f; } v; v.u = ((unsigned)h) << 16;
  return v.f;
}
// pack bf16(s1)<<16 | bf16(s0), round-half-up: 2 adds + 1 v_perm
__device__ __forceinline__ unsigned pack2bf(float s0, float s1) {
  union { float f; unsigned u; } a, b; a.f = s0; b.f = s1;
  return __builtin_amdgcn_perm(b.u + 0x8000u, a.u + 0x8000u, 0x07060302u);
}
__device__ __forceinline__ f32x4 mfma16(s16x8 a, s16x8 b, f32x4 c) {
  return __builtin_amdgcn_mfma_f32_16x16x32_bf16(a, b, c, 0, 0, 0);
}
__device__ __forceinline__ f32x16 mfma32(s16x8 a, s16x8 b, f32x16 c) {
  return __builtin_amdgcn_mfma_f32_32x32x16_bf16(a, b, c, 0, 0, 0);
}
// async 16B/lane global -> LDS (dest = wave-uniform base + lane*16)
__device__ __forceinline__ void async16(const u16* g, u16* l) {
  __builtin_amdgcn_global_load_lds(
      (const __attribute__((address_space(1))) unsigned int*)g,
      (__attribute__((address_space(3))) unsigned int*)l, 16, 0, 0);
}

// ---------------- prep: transpose+cast the 3 weights only ----------------
__device__ __forceinline__ void tr_tile(const float* __restrict__ in, u16* __restrict__ out,
                                        int R, int C, int cx, int ry, int t) {
  __shared__ u16 tile[32][33];
  int tx = t & 31, ty = t >> 5;
  int c0 = cx * 32, r0 = ry * 32;
#pragma unroll
  for (int i = 0; i < 4; i++)
    tile[ty + i * 8][tx] = f2bf(in[(size_t)(r0 + ty + i * 8) * C + c0 + tx]);
  __syncthreads();
#pragma unroll
  for (int i = 0; i < 4; i++)
    out[(size_t)(c0 + ty + i * 8) * R + r0 + tx] = tile[tx][ty + i * 8];
}

__global__ __launch_bounds__(256) void prep_kernel(
    const float* __restrict__ Wq, u16* __restrict__ WqT,
    const float* __restrict__ Wkv, u16* __restrict__ WkvT,
    const float* __restrict__ Wproj, u16* __restrict__ WprT) {
  int bid = blockIdx.x, t = threadIdx.x;
  if (bid < 1024) {
    tr_tile(Wq, WqT, 1024, 1024, bid & 31, bid >> 5, t);
  } else if (bid < 3072) {
    int b2 = bid - 1024;
    tr_tile(Wkv, WkvT, 1024, 2048, b2 & 63, b2 >> 6, t);
  } else {
    int b2 = bid - 3072;
    tr_tile(Wproj, WprT, 1024, 1024, b2 & 31, b2 >> 5, t);
  }
}

// ---------------- fused QKV GEMM: fp32 A staged+cast in-kernel, LN(v)+transpose epilogue ----
// bx 0..7  : qh  = q  @ Wq   cols bx*128       -> bf16 qh (N=1024)
// bx 8..15 : kb  = kv @ Wkv  cols (bx-8)*128   -> bf16 kb (N=1024)
// bx 16..23: v   = kv @ Wkv  cols 1024+...     -> LayerNorm -> vt[b,h,d,s] (transposed)
__global__ __launch_bounds__(256, 3) void gemm_qkv(
    const float* __restrict__ q, const u16* __restrict__ WqT, u16* __restrict__ qh,
    const float* __restrict__ kv, const u16* __restrict__ WkvT, u16* __restrict__ kb,
    const float* __restrict__ gamma, const float* __restrict__ beta, u16* __restrict__ vt) {
  __shared__ __attribute__((aligned(16))) u16 As[128][32];
  __shared__ __attribute__((aligned(16))) u16 Bs[128][32];
  int bx = blockIdx.x;
  int m0 = blockIdx.y * 128;
  const float* A; const u16* BT; int n0;
  if (bx < 8) { A = q; BT = WqT; n0 = bx * 128; }
  else        { A = kv; BT = WkvT; n0 = (bx - 8) * 128; }

  int t = threadIdx.x, w = t >> 6, lane = t & 63;
  int l16 = lane & 15, quad = lane >> 4;
  int mw = (w >> 1) * 64, nw = (w & 1) * 64;
  int arow = t >> 1, acol = (t & 1) * 16;   // A staging: 2 thr/row, 16 fp32 each
  int grow = w * 16 + (lane >> 2);          // B staging row in 64-slab
  int gcol = (lane & 3) * 8;                // B staging col (elems)

  f32x4 acc[4][4] = {};
  float4 a4[4];
  const float* ga = A + (size_t)(m0 + arow) * 1024 + acol;
#pragma unroll
  for (int c = 0; c < 4; c++) a4[c] = *(const float4*)(ga + c * 4);

  for (int kt = 0; kt < 1024; kt += 32) {
    __syncthreads();  // all waves done reading previous slab
    // A: cast fp32 regs -> bf16, 2x b128 LDS writes
    uint4 w0, w1;
    w0.x = pack2bf(a4[0].x, a4[0].y); w0.y = pack2bf(a4[0].z, a4[0].w);
    w0.z = pack2bf(a4[1].x, a4[1].y); w0.w = pack2bf(a4[1].z, a4[1].w);
    w1.x = pack2bf(a4[2].x, a4[2].y); w1.y = pack2bf(a4[2].z, a4[2].w);
    w1.z = pack2bf(a4[3].x, a4[3].y); w1.w = pack2bf(a4[3].z, a4[3].w);
    *(uint4*)&As[arow][acol] = w0;
    *(uint4*)&As[arow][acol + 8] = w1;
    // B: async 16B/lane
#pragma unroll
    for (int j = 0; j < 2; j++)
      async16(BT + (size_t)(n0 + j * 64 + grow) * 1024 + kt + gcol, &Bs[j * 64 + w * 16][0]);
    __syncthreads();  // drains async B + LDS writes
    if (kt + 32 < 1024) {  // prefetch next A slab; overlaps MFMAs
#pragma unroll
      for (int c = 0; c < 4; c++) a4[c] = *(const float4*)(ga + kt + 32 + c * 4);
    }
    s16x8 af[4], bf[4];
#pragma unroll
    for (int i = 0; i < 4; i++) af[i] = *(const s16x8*)&As[mw + i * 16 + l16][quad * 8];
#pragma unroll
    for (int j = 0; j < 4; j++) bf[j] = *(const s16x8*)&Bs[nw + j * 16 + l16][quad * 8];
#pragma unroll
    for (int i = 0; i < 4; i++)
#pragma unroll
      for (int j = 0; j < 4; j++)
        acc[i][j] = mfma16(af[i], bf[j], acc[i][j]);
  }

  if (bx < 16) {
    u16* out = (bx < 8) ? qh : kb;
#pragma unroll
    for (int i = 0; i < 4; i++)
#pragma unroll
      for (int j = 0; j < 4; j++) {
        int col = n0 + nw + j * 16 + l16;
#pragma unroll
        for (int r = 0; r < 4; r++) {
          int row = m0 + mw + i * 16 + quad * 4 + r;
          out[(size_t)row * 1024 + col] = f2bf(acc[i][j][r]);
        }
      }
  } else {
    // v-part: LayerNorm over d (this wave's 64 cols = one head), write vt[b,h,d,s]
    int hh = ((n0 + nw) >> 6) - 16;  // head 0..15
    float gmm[4], bta[4];
#pragma unroll
    for (int j = 0; j < 4; j++) { gmm[j] = gamma[j * 16 + l16]; bta[j] = beta[j * 16 + l16]; }
#pragma unroll
    for (int i = 0; i < 4; i++)
#pragma unroll
      for (int r = 0; r < 4; r++) {
        float sx = 0.0f, sxx = 0.0f;
#pragma unroll
        for (int j = 0; j < 4; j++) {
          float x = acc[i][j][r];
          sx += x; sxx += x * x;
        }
#pragma unroll
        for (int off = 8; off; off >>= 1) {  // reduce across l16 (same quad = same row)
          sx += __shfl_xor(sx, off);
          sxx += __shfl_xor(sxx, off);
        }
        float mu = sx * 0.015625f;
        float var = sxx * 0.015625f - mu * mu;
        float inv = rsqrtf(var + 1e-5f);
        int row = m0 + mw + i * 16 + quad * 4 + r;
        int bb = row >> 11, ss = row & 2047;
        u16* vtp = vt + ((size_t)(bb * 16 + hh) * 64 + l16) * 2048 + ss;
#pragma unroll
        for (int j = 0; j < 4; j++) {
          float y = (acc[i][j][r] - mu) * inv * gmm[j] + bta[j];
          vtp[(size_t)(j * 16) * 2048] = f2bf(y);
        }
      }
  }
}

// ------- m97-style GEMM body (bf16 A via async16), used by proj -------
template <int BM, int BN, bool OUT_BF16>
__device__ __forceinline__ void gemm_body(const u16* __restrict__ A,
                                          const u16* __restrict__ BT,
                                          void* __restrict__ Cout,
                                          int m0, int n0, int N, int K) {
  __shared__ __attribute__((aligned(16))) u16 As[BM][32];
  __shared__ __attribute__((aligned(16))) u16 Bs[BN][32];
  constexpr int AM = BM / 32, AN = BN / 32;
  int t = threadIdx.x, w = t >> 6, lane = t & 63;
  int l16 = lane & 15, quad = lane >> 4;
  int mw = (w >> 1) * (BM / 2), nw = (w & 1) * (BN / 2);
  int grow = w * 16 + (lane >> 2);
  int gcol = (lane & 3) * 8;

  f32x4 acc[AM][AN] = {};

  for (int kt = 0; kt < K; kt += 32) {
    __syncthreads();
#pragma unroll
    for (int j = 0; j < BM / 64; j++)
      async16(A + (size_t)(m0 + j * 64 + grow) * K + kt + gcol, &As[j * 64 + w * 16][0]);
#pragma unroll
    for (int j = 0; j < BN / 64; j++)
      async16(BT + (size_t)(n0 + j * 64 + grow) * K + kt + gcol, &Bs[j * 64 + w * 16][0]);
    __syncthreads();
    s16x8 af[AM], bf[AN];
#pragma unroll
    for (int i = 0; i < AM; i++) af[i] = *(const s16x8*)&As[mw + i * 16 + l16][quad * 8];
#pragma unroll
    for (int j = 0; j < AN; j++) bf[j] = *(const s16x8*)&Bs[nw + j * 16 + l16][quad * 8];
#pragma unroll
    for (int i = 0; i < AM; i++)
#pragma unroll
      for (int j = 0; j < AN; j++)
        acc[i][j] = mfma16(af[i], bf[j], acc[i][j]);
  }

#pragma unroll
  for (int i = 0; i < AM; i++)
#pragma unroll
    for (int j = 0; j < AN; j++) {
      int col = n0 + nw + j * 16 + l16;
#pragma unroll
      for (int r = 0; r < 4; r++) {
        int row = m0 + mw + i * 16 + quad * 4 + r;
        float v = acc[i][j][r];
        if (OUT_BF16)
          ((u16*)Cout)[(size_t)row * N + col] = f2bf(v);
        else
          ((float*)Cout)[(size_t)row * N + col] = v;
      }
    }
}

__global__ __launch_bounds__(256, 3) void gemm_proj(const u16* __restrict__ A,
                                                    const u16* __restrict__ BT,
                                                    float* __restrict__ C) {
  gemm_body<64, 128, false>(A, BT, C, blockIdx.y * 64, blockIdx.x * 128, D_, D_);
}

// ---------------- attention: q64 tiles, grid (32 bh x 32 qt) = 1024 blocks ----------------
// y -> qt DESCENDING (LPT schedule). Wave w: qs=w&1 (q32 strip), kh=w>>1 (k32 half).
// S^T = mfma32(A=K, B=Q) -> sigmoid (v_perm bf16 pack) -> Ps[q][k] (PV A-operand layout)
// -> partial O over k-half; epilogue reduces halves via LDS scratch.
// Strides 68/36/66: measured conflict-free family.
__global__ __launch_bounds__(256, 2) void attn_kernel(const u16* __restrict__ qh,
                                                      const u16* __restrict__ kb,   // (B*SKV) x 1024
                                                      const u16* __restrict__ vt,   // (B*H*HD) x SKV
                                                      float* __restrict__ out0,
                                                      u16* __restrict__ atv_bf) {
  __shared__ __attribute__((aligned(16))) u16 Ks[2][64][68];  // [buf][kv][d] 17408 B
  __shared__ __attribute__((aligned(16))) u16 Vs[2][64][68];  // [buf][d][kv] 17408 B
  __shared__ __attribute__((aligned(16))) u16 Ps[4][32][36];  // [wave][q][k32] 9216 B

  int bh = blockIdx.x;          // 0..31
  int qt = 31 - blockIdx.y;     // descending work size
  int h = bh & 15, b = bh >> 4;
  int t = threadIdx.x;
  int w = t >> 6, lane = t & 63;
  int l31 = lane & 31, hi = lane >> 5;
  int qs = w & 1, kh = w >> 1;
  int srow = t >> 2;            // staging row 0..63
  int scol = (t & 3) * 16;      // staging col (elements)

  const float C1 = -0.18033688011f;  // -0.125 * log2(e)
  const float C2 = 11.5415603272f;   // 8 * log2(e)

  const u16* gkb = kb + ((size_t)(b * SKV_) + srow) * 1024 + h * 64 + scol;
  const u16* gvb = vt + ((size_t)((b * H_ + h) * 64 + srow)) * 2048 + scol;
  float* Osc = (float*)&Ks[0][0][0];  // epilogue scratch alias: 64*66*4 = 16896 <= 17408

  int q0 = qt * 64;
  int nkv = qt + 1;

  // Q fragments (B-operand): lane q = q0 + qs*32 + l31, k_dim d = c*16 + hi*8 + j
  s16x8 qf[4];
  {
    const u16* qp = qh + (size_t)(b * SQ_ + q0 + qs * 32 + l31) * D_ + h * 64 + hi * 8;
#pragma unroll
    for (int c = 0; c < 4; c++) qf[c] = *(const s16x8*)(qp + c * 16);
  }

  f32x16 oacc[2] = {};  // partial O (this wave's k-half): [dt] 32q x 32d

  uint4 kr0 = *(const uint4*)gkb, kr1 = *(const uint4*)(gkb + 8);
  uint4 vr0 = *(const uint4*)gvb, vr1 = *(const uint4*)(gvb + 8);

  for (int kt = 0; kt < nkv; kt++) {
    int buf = kt & 1;
    *(uint4*)&Ks[buf][srow][scol] = kr0; *(uint4*)&Ks[buf][srow][scol + 8] = kr1;
    *(uint4*)&Vs[buf][srow][scol] = vr0; *(uint4*)&Vs[buf][srow][scol + 8] = vr1;
    __syncthreads();  // also separates kt-2 reads from this kt's writes (dbuf)
    if (kt + 1 < nkv) {
      const u16* gk2 = gkb + (size_t)(kt + 1) * 64 * 1024;
      const u16* gv2 = gvb + (size_t)(kt + 1) * 64;
      kr0 = *(const uint4*)gk2; kr1 = *(const uint4*)(gk2 + 8);
      vr0 = *(const uint4*)gv2; vr1 = *(const uint4*)(gv2 + 8);
    }

    // ---- S^T for this wave's k32 x q32 ----
    f32x16 st = {};
#pragma unroll
    for (int c = 0; c < 4; c++) {
      s16x8 kf = *(const s16x8*)&Ks[buf][kh * 32 + l31][c * 16 + hi * 8];
      st = mfma32(kf, qf[c], st);
    }

    // ---- sigmoid (+ causal mask only on the diagonal tile) -> pack into Ps ----
    if (kt == nkv - 1) {
      int qi = q0 + qs * 32 + l31;
      int kbase = kt * 64 + kh * 32 + 4 * hi;
#pragma unroll
      for (int g = 0; g < 4; g++) {
        float pv4[4];
#pragma unroll
        for (int i = 0; i < 4; i++) {
          float s = st[4 * g + i];
          float e = __builtin_amdgcn_exp2f(s * C1 + C2);
          float p = __builtin_amdgcn_rcpf(1.0f + e);
          pv4[i] = (kbase + 8 * g + i > qi) ? 0.0f : p;
        }
        uint2 pv;
        pv.x = pack2bf(pv4[0], pv4[1]);
        pv.y = pack2bf(pv4[2], pv4[3]);
        *(uint2*)&Ps[w][l31][8 * g + 4 * hi] = pv;
      }
    } else {
#pragma unroll
      for (int g = 0; g < 4; g++) {
        float pv4[4];
#pragma unroll
        for (int i = 0; i < 4; i++) {
          float s = st[4 * g + i];
          float e = __builtin_amdgcn_exp2f(s * C1 + C2);
          pv4[i] = __builtin_amdgcn_rcpf(1.0f + e);
        }
        uint2 pv;
        pv.x = pack2bf(pv4[0], pv4[1]);
        pv.y = pack2bf(pv4[2], pv4[3]);
        *(uint2*)&Ps[w][l31][8 * g + 4 * hi] = pv;
      }
    }

    // ---- partial O += P V over this k32 (per-wave Ps: lgkmcnt ordering suffices) ----
    s16x8 pa[2];
#pragma unroll
    for (int kc = 0; kc < 2; kc++)
      pa[kc] = *(const s16x8*)&Ps[w][l31][kc * 16 + hi * 8];
#pragma unroll
    for (int dt = 0; dt < 2; dt++)
#pragma unroll
      for (int kc = 0; kc < 2; kc++) {
        s16x8 vf = *(const s16x8*)&Vs[buf][dt * 32 + l31][kh * 32 + kc * 16 + hi * 8];
        oacc[dt] = mfma32(pa[kc], vf, oacc[dt]);
      }
  }

  // ---- epilogue: reduce the two k-halves via LDS scratch, then store ----
  __syncthreads();  // all K/V reads done; Ks space reusable as Osc
  if (kh == 1) {
#pragma unroll
    for (int dt = 0; dt < 2; dt++)
#pragma unroll
      for (int reg = 0; reg < 16; reg++) {
        int ql = (reg & 3) + 8 * (reg >> 2) + 4 * hi;
        Osc[(qs * 32 + ql) * 66 + dt * 32 + l31] = oacc[dt][reg];
      }
  }
  __syncthreads();
  if (kh == 0) {
#pragma unroll
    for (int dt = 0; dt < 2; dt++)
#pragma unroll
      for (int reg = 0; reg < 16; reg++) {
        int ql = (reg & 3) + 8 * (reg >> 2) + 4 * hi;
        float v = oacc[dt][reg] + Osc[(qs * 32 + ql) * 66 + dt * 32 + l31];
        int row = q0 + qs * 32 + ql;
        int col = h * 64 + dt * 32 + l31;
        size_t idx = (size_t)(b * SQ_ + row) * D_ + col;
        out0[idx] = v;
        atv_bf[idx] = f2bf(v);
      }
  }
}

extern "C" void kernel_launch(void* const* d_in, const int* in_sizes, int n_in,
                              void* d_out, int out_size, void* d_ws, size_t ws_size,
                              hipStream_t stream) {
  const float* q      = (const float*)d_in[0];
  const float* kv     = (const float*)d_in[1];
  const float* Wq     = (const float*)d_in[2];
  const float* Wkv    = (const float*)d_in[3];
  const float* vgamma = (const float*)d_in[4];
  const float* vbeta  = (const float*)d_in[5];
  const float* Wproj  = (const float*)d_in[6];
  float* out0 = (float*)d_out;
  float* out1 = out0 + (size_t)B_ * SQ_ * D_;

  char* p = (char*)d_ws;
  u16* WqT  = (u16*)p; p += (size_t)D_ * D_ * 2;               // 2 MB
  u16* WkvT = (u16*)p; p += (size_t)2 * D_ * D_ * 2;           // 4 MB
  u16* WprT = (u16*)p; p += (size_t)D_ * D_ * 2;               // 2 MB
  u16* qh   = (u16*)p; p += (size_t)B_ * SQ_ * D_ * 2;         // 8 MB
  u16* kb   = (u16*)p; p += (size_t)B_ * SKV_ * D_ * 2;        // 8 MB
  u16* vt   = (u16*)p; p += (size_t)B_ * H_ * HD_ * SKV_ * 2;  // 8 MB
  u16* atv  = (u16*)p; p += (size_t)B_ * SQ_ * D_ * 2;         // 8 MB

  prep_kernel<<<dim3(4096), 256, 0, stream>>>(Wq, WqT, Wkv, WkvT, Wproj, WprT);

  gemm_qkv<<<dim3(24, 32), 256, 0, stream>>>(q, WqT, qh, kv, WkvT, kb, vgamma, vbeta, vt);

  attn_kernel<<<dim3(32, 32), 256, 0, stream>>>(qh, kb, vt, out0, atv);

  gemm_proj<<<dim3(8, 64), 256, 0, stream>>>(atv, WprT, out1);
}